// Round 5
// baseline (1374.559 us; speedup 1.0000x reference)
//
#include <hip/hip_runtime.h>
#include <cstdint>

typedef float f32x4 __attribute__((ext_vector_type(4)));
typedef __bf16 bf16x8 __attribute__((ext_vector_type(8)));
typedef unsigned short us8 __attribute__((ext_vector_type(8)));

#define T2 126

__device__ __forceinline__ unsigned short f2bf(float x){
  union { float f; uint32_t u; } v; v.f = x;
  return (unsigned short)((v.u + 0x7fffu + ((v.u >> 16) & 1u)) >> 16);
}
__device__ __forceinline__ float bf2f(unsigned short h){
  union { uint32_t u; float f; } v; v.u = ((uint32_t)h) << 16; return v.f;
}
__device__ __forceinline__ f32x4 mfma_bf16(us8 a, us8 b, f32x4 c){
  return __builtin_amdgcn_mfma_f32_16x16x32_bf16(
      __builtin_bit_cast(bf16x8, a), __builtin_bit_cast(bf16x8, b), c, 0, 0, 0);
}
__device__ __forceinline__ float sigm(float x){ return 1.0f / (1.0f + __expf(-x)); }

// XOR-swizzled LDS address for a [rows][512] bf16 tile, 8-short chunks.
#define HSWZ(row, chunk) ((row) * 512 + ((((chunk) ^ ((row) & 7))) << 3))

// ---------------------------------------------------------------------------
// Pack (1536,512) fp32 weights -> bf16 MFMA B-fragments.
// Tile (jt,kt): lane l elem e holds W[16jt+(l&15)][32kt+8*(l>>4)+e]
// at dst[(jt*16+kt)*512 + l*8 + e]
// ---------------------------------------------------------------------------
__global__ void __launch_bounds__(256) pack_w_kernel(const float* __restrict__ w,
                                                     unsigned short* __restrict__ dst){
  int tid = blockIdx.x * 256 + threadIdx.x;     // 0..98303
  int l = tid & 63;
  int tile = tid >> 6;                          // jt*16 + kt
  int kt = tile & 15, jt = tile >> 4;
  int row = jt * 16 + (l & 15);
  int col = kt * 32 + (l >> 4) * 8;
  const float* s = w + (size_t)row * 512 + col;
  unsigned short o[8];
  #pragma unroll
  for (int e = 0; e < 8; e++) o[e] = f2bf(s[e]);
  *(us8*)(dst + (size_t)tid * 8) = *(const us8*)o;
}

// ---------------------------------------------------------------------------
// Fused conv+GELU+GEMM: gates_c = gelu(conv(frames)) @ w_ih^T + b_ih.
// Block = 64 samples x 1536 cols, 256 thr (4 waves).
// Stage: each thread computes 4 (sample,patch) conv tasks (32 outs each,
// exact-erf GELU) directly into the XOR-swizzled LDS A-tile. Then the
// MFMA loop (B streamed from packed wih_p, L2-resident).
// ---------------------------------------------------------------------------
__global__ void __launch_bounds__(256) gates_gemm_kernel(const float* __restrict__ frames,
                                                         const float* __restrict__ cw,
                                                         const float* __restrict__ cb,
                                                         const unsigned short* __restrict__ wih_p,
                                                         const float* __restrict__ b_ih,
                                                         unsigned short* __restrict__ gates_c,
                                                         int t0, int Tc){
  __shared__ unsigned short alds[64 * 512];
  __shared__ float wl[1024];
  __shared__ float cbl[32];
  int tid = threadIdx.x;
  int m0 = blockIdx.x * 64;
  #pragma unroll
  for (int i = 0; i < 4; i++) wl[tid + 256 * i] = cw[tid + 256 * i];
  if (tid < 32) cbl[tid] = cb[tid];
  __syncthreads();
  // conv+gelu stage into A-tile
  #pragma unroll
  for (int tk = 0; tk < 4; tk++){
    int task = tid + 256 * tk;            // 0..1023 = 64 samples x 16 patches
    int s = task >> 4, patch = task & 15;
    int n = m0 + s;
    int b = n / Tc, tl = n - b * Tc;
    int t = t0 + tl;
    const float* fb = frames + ((size_t)b * 128 + t) * 256;  // frame t (prev)
    int ii = patch >> 2, jj = patch & 3;
    float4 pv[4], cv[4];
    #pragma unroll
    for (int p = 0; p < 4; p++){
      int base = (ii * 4 + p) * 16 + jj * 4;
      pv[p] = *(const float4*)(fb + base);          // prev = frame t
      cv[p] = *(const float4*)(fb + 256 + base);    // curr = frame t+1
    }
    #pragma unroll
    for (int o = 0; o < 32; o++){
      const float* wc = &wl[o * 32];
      float acc = cbl[o];
      #pragma unroll
      for (int p = 0; p < 4; p++){
        acc += cv[p].x * wc[p*4+0] + cv[p].y * wc[p*4+1]
             + cv[p].z * wc[p*4+2] + cv[p].w * wc[p*4+3];
        acc += pv[p].x * wc[16+p*4+0] + pv[p].y * wc[16+p*4+1]
             + pv[p].z * wc[16+p*4+2] + pv[p].w * wc[16+p*4+3];
      }
      float g = 0.5f * acc * (1.0f + erff(acc * 0.70710678118654752f));
      int col = o * 16 + patch;
      alds[HSWZ(s, col >> 3) + (col & 7)] = f2bf(g);
    }
  }
  __syncthreads();
  int l = tid & 63, w = tid >> 6;
  int lr = l & 15, lh = l >> 4;
  for (int jg = 0; jg < 6; jg++){
    int jt0 = w * 24 + jg * 4;
    f32x4 acc[4][4];
    #pragma unroll
    for (int mt = 0; mt < 4; mt++)
      #pragma unroll
      for (int jj = 0; jj < 4; jj++) acc[mt][jj] = (f32x4){0.f,0.f,0.f,0.f};
    #pragma unroll
    for (int kt = 0; kt < 16; kt++){
      us8 a[4], bf[4];
      #pragma unroll
      for (int mt = 0; mt < 4; mt++){
        int row = mt * 16 + lr;
        int ch = kt * 4 + lh;
        a[mt] = *(const us8*)&alds[HSWZ(row, ch)];
      }
      #pragma unroll
      for (int jj = 0; jj < 4; jj++)
        bf[jj] = *(const us8*)(wih_p + ((size_t)((jt0 + jj) * 16 + kt) * 512 + l * 8));
      #pragma unroll
      for (int mt = 0; mt < 4; mt++)
        #pragma unroll
        for (int jj = 0; jj < 4; jj++)
          acc[mt][jj] = mfma_bf16(a[mt], bf[jj], acc[mt][jj]);
    }
    #pragma unroll
    for (int jj = 0; jj < 4; jj++){
      int j = (jt0 + jj) * 16 + lr;
      float bias = b_ih[j];
      #pragma unroll
      for (int mt = 0; mt < 4; mt++)
        #pragma unroll
        for (int r = 0; r < 4; r++){
          int m = m0 + mt * 16 + lh * 4 + r;
          gates_c[(size_t)m * 1536 + j] = f2bf(acc[mt][jj][r] + bias);
        }
    }
  }
}

// ---------------------------------------------------------------------------
// One-time init per kernel_launch: zero flags and h_glob (h(0) = 0).
// NOT re-run between chunks (flags carry global step numbers).
// ---------------------------------------------------------------------------
__global__ void __launch_bounds__(256) scan_init_kernel(unsigned int* __restrict__ flags,
                                                        unsigned short* __restrict__ h_glob){
  int tid = blockIdx.x * 256 + threadIdx.x;
  if (tid < 256) flags[tid] = 0;
  for (int i = tid; i < 2 * 512 * 512; i += gridDim.x * 256)
    h_glob[i] = 0;
}

// ---------------------------------------------------------------------------
// Weight-stationary persistent GRU scan — fence-free, latency-trimmed.
// Grid = 256 blocks = 16 batch-groups (32 rows) x 16 hidden-slices (32 cols).
// w_hh fragments pinned in VGPR/AGPRs via volatile loads. Flags hold GLOBAL
// step numbers (monotone across chunks; init once per launch). Per step:
// gx prefetch || spin(flag >= s) -> stage h(s) (coherent u64 loads) -> LDS
// -> 48 MFMA -> gate math -> 4 h-stores -> vmcnt(0) (ONLY h-stores pending)
// -> barrier -> publish s+1 -> outs stores (off critical path).
// ---------------------------------------------------------------------------
__global__ void __launch_bounds__(256, 1) gru_scan_kernel(
    const unsigned short* __restrict__ gates_c,
    const unsigned short* __restrict__ whh_p,
    const float* __restrict__ b_hh,
    unsigned short* __restrict__ h_glob,   // [2][512][512] bf16
    float* __restrict__ h_state,           // [512][512] fp32 chunk carry
    unsigned int* __restrict__ flags,      // [16 groups][16 slices], global step
    unsigned short* __restrict__ outs_c,
    int Tc, int t0){
  __shared__ unsigned short hlds[32 * 512];
  const int tid = threadIdx.x;
  const int B = blockIdx.x;
  const int grp = (B & 7) * 2 + ((B >> 3) >> 4);   // 0..15, same-XCD cluster
  const int slc = (B >> 3) & 15;                   // 0..15
  const int l = tid & 63;
  const int w = tid >> 6;                          // wave 0..3
  const int mt = w & 1, jg = w >> 1;
  const int lr = l & 15, lh = l >> 4;
  const int j = slc * 32 + jg * 16 + lr;           // hidden col
  const int rowbase = grp * 32 + mt * 16 + lh * 4; // + r = batch row

  // persistent weight fragments, pinned via volatile loads
  us8 wr[16], wz[16], wn[16];
  {
    const int jtR = slc * 2 + jg;
    #pragma unroll
    for (int kt = 0; kt < 16; kt++){
      wr[kt] = *(volatile const us8*)(whh_p + ((size_t)((jtR      ) * 16 + kt) * 512 + l * 8));
      wz[kt] = *(volatile const us8*)(whh_p + ((size_t)((jtR + 32) * 16 + kt) * 512 + l * 8));
      wn[kt] = *(volatile const us8*)(whh_p + ((size_t)((jtR + 64) * 16 + kt) * 512 + l * 8));
    }
  }
  const float bhr = b_hh[j], bhz = b_hh[512 + j], bhn = b_hh[1024 + j];
  float hprev[4];
  if (t0 == 0){
    hprev[0] = hprev[1] = hprev[2] = hprev[3] = 0.0f;
  } else {
    #pragma unroll
    for (int r = 0; r < 4; r++) hprev[r] = h_state[(size_t)(rowbase + r) * 512 + j];
  }
  unsigned int* gflag = flags + grp * 16;

  for (int tl = 0; tl < Tc; tl++){
    const int s = t0 + tl;
    const unsigned short* hbuf = h_glob + (size_t)(s & 1) * (512 * 512);
    unsigned short* hnext = h_glob + (size_t)((s + 1) & 1) * (512 * 512);
    // prefetch gx for this step (overlaps the spin)
    float gxr[4], gxz[4], gxn[4];
    #pragma unroll
    for (int r = 0; r < 4; r++){
      size_t gb = ((size_t)(rowbase + r) * Tc + tl) * 1536;
      gxr[r] = bf2f(gates_c[gb + j]);
      gxz[r] = bf2f(gates_c[gb + 512 + j]);
      gxn[r] = bf2f(gates_c[gb + 1024 + j]);
    }
    // wait until every slice of this group has published h(s)
    if (tid < 16){
      while ((int)__hip_atomic_load(&gflag[tid], __ATOMIC_RELAXED,
                                    __HIP_MEMORY_SCOPE_AGENT) < s)
        __builtin_amdgcn_s_sleep(1);
    }
    __syncthreads();                 // all past wait; WAR for hlds restage
    // stage h(s) rows [grp*32, grp*32+32) into LDS via coherent u64 loads
    #pragma unroll
    for (int it = 0; it < 8; it++){
      int cid = tid + 256 * it;
      int row = cid >> 6, ch = cid & 63;
      unsigned long long* src = (unsigned long long*)(hbuf + (size_t)(grp * 32 + row) * 512 + ch * 8);
      unsigned long long lo = __hip_atomic_load(src,     __ATOMIC_RELAXED, __HIP_MEMORY_SCOPE_AGENT);
      unsigned long long hi = __hip_atomic_load(src + 1, __ATOMIC_RELAXED, __HIP_MEMORY_SCOPE_AGENT);
      union { unsigned long long q[2]; us8 v; } u;
      u.q[0] = lo; u.q[1] = hi;
      *(us8*)&hlds[HSWZ(row, ch)] = u.v;
    }
    __syncthreads();
    f32x4 aR = {0.f,0.f,0.f,0.f}, aZ = {0.f,0.f,0.f,0.f}, aN = {0.f,0.f,0.f,0.f};
    #pragma unroll
    for (int kt = 0; kt < 16; kt++){
      us8 a = *(const us8*)&hlds[HSWZ(mt * 16 + lr, kt * 4 + lh)];
      aR = mfma_bf16(a, wr[kt], aR);
      aZ = mfma_bf16(a, wz[kt], aZ);
      aN = mfma_bf16(a, wn[kt], aN);
    }
    unsigned short hb[4];
    #pragma unroll
    for (int r = 0; r < 4; r++){
      float rr = sigm(gxr[r] + aR[r] + bhr);
      float zz = sigm(gxz[r] + aZ[r] + bhz);
      float nn = tanhf(gxn[r] + rr * (aN[r] + bhn));
      float hv = (1.0f - zz) * nn + zz * hprev[r];
      hprev[r] = hv;
      hb[r] = f2bf(hv);
      __hip_atomic_store(&hnext[(size_t)(rowbase + r) * 512 + j], hb[r],
                         __ATOMIC_RELAXED, __HIP_MEMORY_SCOPE_AGENT);
    }
    asm volatile("s_waitcnt vmcnt(0)" ::: "memory");  // only h stores pending
    __syncthreads();                 // all waves of this block done
    if (tid == 0)
      __hip_atomic_store(&gflag[slc], (unsigned)(s + 1), __ATOMIC_RELAXED,
                         __HIP_MEMORY_SCOPE_AGENT);
    // outs stores off the critical path
    #pragma unroll
    for (int r = 0; r < 4; r++)
      outs_c[((size_t)(rowbase + r) * Tc + tl) * 512 + j] = hb[r];
  }
  // fp32 carry for next chunk
  #pragma unroll
  for (int r = 0; r < 4; r++)
    h_state[(size_t)(rowbase + r) * 512 + j] = hprev[r];
}

// ---------------------------------------------------------------------------
// Deconv + tanh + residual + clip -> fp32 output
// ---------------------------------------------------------------------------
__global__ void __launch_bounds__(256) deconv_kernel(const unsigned short* __restrict__ outs_c,
                                                     const float* __restrict__ dw,
                                                     const float* __restrict__ db,
                                                     const float* __restrict__ frames,
                                                     float* __restrict__ out,
                                                     int t0, int Tc){
  __shared__ float wl[512];
  __shared__ float dv[512];
  int n = blockIdx.x;
  int b = n / Tc, tl = n - b * Tc;
  int t = t0 + tl;
  int tid = threadIdx.x;
  wl[tid] = dw[tid]; wl[tid + 256] = dw[tid + 256];
  dv[tid] = bf2f(outs_c[(size_t)n * 512 + tid]);
  dv[tid + 256] = bf2f(outs_c[(size_t)n * 512 + tid + 256]);
  __syncthreads();
  int row = tid >> 4, col = tid & 15;
  int ii = row >> 2, p = row & 3, jj = col >> 2, q = col & 3;
  float s = db[0];
  #pragma unroll
  for (int c = 0; c < 32; c++)
    s += dv[c * 16 + ii * 4 + jj] * wl[c * 16 + p * 4 + q];
  float d = tanhf(s);
  float cv = frames[((size_t)b * 128 + (t + 1)) * 256 + tid];
  float r = cv + d;
  out[((size_t)b * T2 + t) * 256 + tid] = fminf(fmaxf(r, 0.0f), 1.0f);
}

extern "C" void kernel_launch(void* const* d_in, const int* in_sizes, int n_in,
                              void* d_out, int out_size, void* d_ws, size_t ws_size,
                              hipStream_t stream) {
  const float* frames   = (const float*)d_in[0];
  const float* conv_w   = (const float*)d_in[1];
  const float* conv_b   = (const float*)d_in[2];
  const float* w_ih     = (const float*)d_in[3];
  const float* w_hh     = (const float*)d_in[4];
  const float* b_ih     = (const float*)d_in[5];
  const float* b_hh     = (const float*)d_in[6];
  const float* deconv_w = (const float*)d_in[7];
  const float* deconv_b = (const float*)d_in[8];
  float* out = (float*)d_out;
  char* ws = (char*)d_ws;

  // fixed region: wih_p 1.5M | whh_p 1.5M | h_state 1M | h_glob 1M | flags 4K
  unsigned short* wih_p   = (unsigned short*)(ws);
  unsigned short* whh_p   = (unsigned short*)(ws + 1572864LL);
  float*          h_state = (float*)         (ws + 3145728LL);
  unsigned short* h_glob  = (unsigned short*)(ws + 4194304LL);
  unsigned int*   flags   = (unsigned int*)  (ws + 5242880LL);
  char*           chunkws = ws + 5246976LL;

  // chunked region: gates 1.5M/t + outs 0.5M/t (feat eliminated by fusion)
  static const int divs[12] = {126, 63, 42, 21, 18, 14, 9, 7, 6, 3, 2, 1};
  int Tc = 1;
  for (int i = 0; i < 12; i++){
    long long need = 5246976LL + 2097152LL * divs[i];
    if (need <= (long long)ws_size){ Tc = divs[i]; break; }
  }
  int G = T2 / Tc;

  unsigned short* gates_c = (unsigned short*)(chunkws);
  unsigned short* outs_c  = (unsigned short*)(chunkws + 1572864LL * Tc);

  pack_w_kernel<<<384, 256, 0, stream>>>(w_ih, wih_p);
  pack_w_kernel<<<384, 256, 0, stream>>>(w_hh, whh_p);
  scan_init_kernel<<<64, 256, 0, stream>>>(flags, h_glob);

  for (int c = 0; c < G; c++){
    int t0 = c * Tc;
    gates_gemm_kernel<<<8 * Tc, 256, 0, stream>>>(frames, conv_w, conv_b, wih_p,
                                                  b_ih, gates_c, t0, Tc);
    gru_scan_kernel<<<256, 256, 0, stream>>>(gates_c, whh_p, b_hh, h_glob, h_state,
                                             flags, outs_c, Tc, t0);
    deconv_kernel<<<512 * Tc, 256, 0, stream>>>(outs_c, deconv_w, deconv_b, frames, out, t0, Tc);
  }
}

// Round 6
// 1313.198 us; speedup vs baseline: 1.0467x; 1.0467x over previous
//
#include <hip/hip_runtime.h>
#include <cstdint>

typedef float f32x4 __attribute__((ext_vector_type(4)));
typedef __bf16 bf16x8 __attribute__((ext_vector_type(8)));
typedef unsigned short us8 __attribute__((ext_vector_type(8)));

#define T2 126

__device__ __forceinline__ unsigned short f2bf(float x){
  union { float f; uint32_t u; } v; v.f = x;
  return (unsigned short)((v.u + 0x7fffu + ((v.u >> 16) & 1u)) >> 16);
}
__device__ __forceinline__ float bf2f(unsigned short h){
  union { uint32_t u; float f; } v; v.u = ((uint32_t)h) << 16; return v.f;
}
__device__ __forceinline__ f32x4 mfma_bf16(us8 a, us8 b, f32x4 c){
  return __builtin_amdgcn_mfma_f32_16x16x32_bf16(
      __builtin_bit_cast(bf16x8, a), __builtin_bit_cast(bf16x8, b), c, 0, 0, 0);
}
__device__ __forceinline__ float sigm(float x){ return 1.0f / (1.0f + __expf(-x)); }

// XOR-swizzled LDS address for a [rows][512] bf16 tile, 8-short chunks.
#define HSWZ(row, chunk) ((row) * 512 + ((((chunk) ^ ((row) & 7))) << 3))

// ---------------------------------------------------------------------------
// Pack (1536,512) fp32 weights -> bf16 MFMA B-fragments.
// Tile (jt,kt): lane l elem e holds W[16jt+(l&15)][32kt+8*(l>>4)+e]
// at dst[(jt*16+kt)*512 + l*8 + e]
// ---------------------------------------------------------------------------
__global__ void __launch_bounds__(256) pack_w_kernel(const float* __restrict__ w,
                                                     unsigned short* __restrict__ dst){
  int tid = blockIdx.x * 256 + threadIdx.x;     // 0..98303
  int l = tid & 63;
  int tile = tid >> 6;                          // jt*16 + kt
  int kt = tile & 15, jt = tile >> 4;
  int row = jt * 16 + (l & 15);
  int col = kt * 32 + (l >> 4) * 8;
  const float* s = w + (size_t)row * 512 + col;
  unsigned short o[8];
  #pragma unroll
  for (int e = 0; e < 8; e++) o[e] = f2bf(s[e]);
  *(us8*)(dst + (size_t)tid * 8) = *(const us8*)o;
}

// ---------------------------------------------------------------------------
// Fused conv+GELU+GEMM: gates_c = gelu(conv(frames)) @ w_ih^T + b_ih.
// Block = 64 samples x 1536 cols, 256 thr (4 waves).
// ---------------------------------------------------------------------------
__global__ void __launch_bounds__(256) gates_gemm_kernel(const float* __restrict__ frames,
                                                         const float* __restrict__ cw,
                                                         const float* __restrict__ cb,
                                                         const unsigned short* __restrict__ wih_p,
                                                         const float* __restrict__ b_ih,
                                                         unsigned short* __restrict__ gates_c,
                                                         int t0, int Tc){
  __shared__ unsigned short alds[64 * 512];
  __shared__ float wl[1024];
  __shared__ float cbl[32];
  int tid = threadIdx.x;
  int m0 = blockIdx.x * 64;
  #pragma unroll
  for (int i = 0; i < 4; i++) wl[tid + 256 * i] = cw[tid + 256 * i];
  if (tid < 32) cbl[tid] = cb[tid];
  __syncthreads();
  // conv+gelu stage into A-tile
  #pragma unroll
  for (int tk = 0; tk < 4; tk++){
    int task = tid + 256 * tk;            // 0..1023 = 64 samples x 16 patches
    int s = task >> 4, patch = task & 15;
    int n = m0 + s;
    int b = n / Tc, tl = n - b * Tc;
    int t = t0 + tl;
    const float* fb = frames + ((size_t)b * 128 + t) * 256;  // frame t (prev)
    int ii = patch >> 2, jj = patch & 3;
    float4 pv[4], cv[4];
    #pragma unroll
    for (int p = 0; p < 4; p++){
      int base = (ii * 4 + p) * 16 + jj * 4;
      pv[p] = *(const float4*)(fb + base);          // prev = frame t
      cv[p] = *(const float4*)(fb + 256 + base);    // curr = frame t+1
    }
    #pragma unroll
    for (int o = 0; o < 32; o++){
      const float* wc = &wl[o * 32];
      float acc = cbl[o];
      #pragma unroll
      for (int p = 0; p < 4; p++){
        acc += cv[p].x * wc[p*4+0] + cv[p].y * wc[p*4+1]
             + cv[p].z * wc[p*4+2] + cv[p].w * wc[p*4+3];
        acc += pv[p].x * wc[16+p*4+0] + pv[p].y * wc[16+p*4+1]
             + pv[p].z * wc[16+p*4+2] + pv[p].w * wc[16+p*4+3];
      }
      float g = 0.5f * acc * (1.0f + erff(acc * 0.70710678118654752f));
      int col = o * 16 + patch;
      alds[HSWZ(s, col >> 3) + (col & 7)] = f2bf(g);
    }
  }
  __syncthreads();
  int l = tid & 63, w = tid >> 6;
  int lr = l & 15, lh = l >> 4;
  for (int jg = 0; jg < 6; jg++){
    int jt0 = w * 24 + jg * 4;
    f32x4 acc[4][4];
    #pragma unroll
    for (int mt = 0; mt < 4; mt++)
      #pragma unroll
      for (int jj = 0; jj < 4; jj++) acc[mt][jj] = (f32x4){0.f,0.f,0.f,0.f};
    #pragma unroll
    for (int kt = 0; kt < 16; kt++){
      us8 a[4], bf[4];
      #pragma unroll
      for (int mt = 0; mt < 4; mt++){
        int row = mt * 16 + lr;
        int ch = kt * 4 + lh;
        a[mt] = *(const us8*)&alds[HSWZ(row, ch)];
      }
      #pragma unroll
      for (int jj = 0; jj < 4; jj++)
        bf[jj] = *(const us8*)(wih_p + ((size_t)((jt0 + jj) * 16 + kt) * 512 + l * 8));
      #pragma unroll
      for (int mt = 0; mt < 4; mt++)
        #pragma unroll
        for (int jj = 0; jj < 4; jj++)
          acc[mt][jj] = mfma_bf16(a[mt], bf[jj], acc[mt][jj]);
    }
    #pragma unroll
    for (int jj = 0; jj < 4; jj++){
      int j = (jt0 + jj) * 16 + lr;
      float bias = b_ih[j];
      #pragma unroll
      for (int mt = 0; mt < 4; mt++)
        #pragma unroll
        for (int r = 0; r < 4; r++){
          int m = m0 + mt * 16 + lh * 4 + r;
          gates_c[(size_t)m * 1536 + j] = f2bf(acc[mt][jj][r] + bias);
        }
    }
  }
}

// ---------------------------------------------------------------------------
// One-time init per kernel_launch: zero flags and h_glob (h(0)=0).
// ---------------------------------------------------------------------------
__global__ void __launch_bounds__(256) scan_init_kernel(unsigned int* __restrict__ flags,
                                                        unsigned short* __restrict__ h_glob){
  int tid = blockIdx.x * 256 + threadIdx.x;
  if (tid < 256) flags[tid] = 0;
  for (int i = tid; i < 2 * 512 * 512; i += gridDim.x * 256)
    h_glob[i] = 0;
}

// ---------------------------------------------------------------------------
// Weight-stationary persistent GRU scan + fused deconv output.
// Grid = 256 blocks = 32 batch-groups (16 rows) x 8 hidden-slices (64 cols).
// B = slc*32 + grp so a group's 8 blocks share B%8 (same-XCD heuristic).
// Per wave: one 16-col j-tile x 3 gates = 48 weight frags pinned in regs
// (volatile loads). Per step: gx prefetch || spin(8 flags) -> stage 16x512
// h(s) (coherent u64 loads) -> 48 MFMA -> gate math -> h to LDS -> one
// coalesced 8B agent-atomic store/thread -> vmcnt(0) -> publish flag ->
// fused deconv emits out[:, s-1] from hlds (in the publish->observe shadow).
// ---------------------------------------------------------------------------
__global__ void __launch_bounds__(256, 1) gru_scan_kernel(
    const unsigned short* __restrict__ gates_c,
    const unsigned short* __restrict__ whh_p,
    const float* __restrict__ b_hh,
    unsigned short* __restrict__ h_glob,   // [2][512][512] bf16
    float* __restrict__ h_state,           // [512][512] fp32 chunk carry
    unsigned int* __restrict__ flags,      // [32 groups][8 slices], global step
    const float* __restrict__ frames,
    const float* __restrict__ dw,
    const float* __restrict__ db,
    float* __restrict__ out,
    int Tc, int t0){
  __shared__ unsigned short hlds[16 * 512];   // h(s) slab, swizzled
  __shared__ unsigned short hout[16 * 64];    // block's h(s+1) tile
  __shared__ float dwl[512];                  // deconv weights
  const int tid = threadIdx.x;
  const int B = blockIdx.x;
  const int grp = B & 31;                     // batch group 0..31
  const int slc = B >> 5;                     // hidden slice 0..7
  const int l = tid & 63;
  const int w = tid >> 6;                     // wave 0..3
  const int lr = l & 15, lh = l >> 4;
  const int j = slc * 64 + w * 16 + lr;       // hidden col
  const int rowb = grp * 16;                  // batch row base
  const int rloc = lh * 4;                    // + r = local row

  dwl[tid] = dw[tid]; dwl[tid + 256] = dw[tid + 256];
  const float dbias = db[0];

  // persistent weight fragments, pinned via volatile loads
  us8 wr[16], wz[16], wn[16];
  {
    const int jt = slc * 4 + w;
    #pragma unroll
    for (int kt = 0; kt < 16; kt++){
      wr[kt] = *(volatile const us8*)(whh_p + ((size_t)((jt      ) * 16 + kt) * 512 + l * 8));
      wz[kt] = *(volatile const us8*)(whh_p + ((size_t)((jt + 32) * 16 + kt) * 512 + l * 8));
      wn[kt] = *(volatile const us8*)(whh_p + ((size_t)((jt + 64) * 16 + kt) * 512 + l * 8));
    }
  }
  const float bhr = b_hh[j], bhz = b_hh[512 + j], bhn = b_hh[1024 + j];
  float hprev[4];
  if (t0 == 0){
    hprev[0] = hprev[1] = hprev[2] = hprev[3] = 0.0f;
  } else {
    #pragma unroll
    for (int r = 0; r < 4; r++) hprev[r] = h_state[(size_t)(rowb + rloc + r) * 512 + j];
  }
  unsigned int* gflag = flags + grp * 8;

  // fused deconv: emit out[:, so] from hlds (= outs[so]); residual frames[b][so+1]
  auto emit = [&](int so){
    int row = tid >> 4;                       // sample row 0..15
    int b = rowb + row;
    const float* fr = frames + ((size_t)b * 128 + so + 1) * 256;
    float* ob = out + ((size_t)b * T2 + so) * 256;
    #pragma unroll
    for (int e = 0; e < 2; e++){
      int pi = (tid & 15) * 2 + e;            // 0..31
      int pr = slc * 2 + (pi >> 4), pc = pi & 15;
      int ii = pr >> 2, pp = pr & 3, jj = pc >> 2, qq = pc & 3;
      float acc = dbias;
      #pragma unroll
      for (int c = 0; c < 32; c++){
        int ch = c * 16 + ii * 4 + jj;
        acc += bf2f(hlds[HSWZ(row, ch >> 3) + (ch & 7)]) * dwl[c * 16 + pp * 4 + qq];
      }
      float dlt = tanhf(acc);
      float rv = fr[pr * 16 + pc] + dlt;
      ob[pr * 16 + pc] = fminf(fmaxf(rv, 0.0f), 1.0f);
    }
  };

  for (int tl = 0; tl < Tc; tl++){
    const int s = t0 + tl;
    const unsigned short* hbuf = h_glob + (size_t)(s & 1) * (512 * 512);
    unsigned short* hnext = h_glob + (size_t)((s + 1) & 1) * (512 * 512);
    // prefetch gx for this step (overlaps the spin)
    float gxr[4], gxz[4], gxn[4];
    #pragma unroll
    for (int r = 0; r < 4; r++){
      size_t gb = ((size_t)(rowb + rloc + r) * Tc + tl) * 1536;
      gxr[r] = bf2f(gates_c[gb + j]);
      gxz[r] = bf2f(gates_c[gb + 512 + j]);
      gxn[r] = bf2f(gates_c[gb + 1024 + j]);
    }
    // wait until every slice of this group has published h(s)
    if (tid < 8){
      while ((int)__hip_atomic_load(&gflag[tid], __ATOMIC_RELAXED,
                                    __HIP_MEMORY_SCOPE_AGENT) < s)
        __builtin_amdgcn_s_sleep(1);
    }
    __syncthreads();                 // all past wait; WAR for hlds/hout
    // stage h(s) rows [rowb, rowb+16) into LDS via coherent u64 loads
    #pragma unroll
    for (int it = 0; it < 4; it++){
      int cid = tid + 256 * it;              // 0..1023
      int row = cid >> 6, ch = cid & 63;
      unsigned long long* src = (unsigned long long*)(hbuf + (size_t)(rowb + row) * 512 + ch * 8);
      unsigned long long lo = __hip_atomic_load(src,     __ATOMIC_RELAXED, __HIP_MEMORY_SCOPE_AGENT);
      unsigned long long hi = __hip_atomic_load(src + 1, __ATOMIC_RELAXED, __HIP_MEMORY_SCOPE_AGENT);
      union { unsigned long long q[2]; us8 v; } u;
      u.q[0] = lo; u.q[1] = hi;
      *(us8*)&hlds[HSWZ(row, ch)] = u.v;
    }
    __syncthreads();
    f32x4 aR = {0.f,0.f,0.f,0.f}, aZ = {0.f,0.f,0.f,0.f}, aN = {0.f,0.f,0.f,0.f};
    #pragma unroll
    for (int kt = 0; kt < 16; kt++){
      us8 a = *(const us8*)&hlds[HSWZ(lr, kt * 4 + lh)];
      aR = mfma_bf16(a, wr[kt], aR);
      aZ = mfma_bf16(a, wz[kt], aZ);
      aN = mfma_bf16(a, wn[kt], aN);
    }
    #pragma unroll
    for (int r = 0; r < 4; r++){
      float rr = sigm(gxr[r] + aR[r] + bhr);
      float zz = sigm(gxz[r] + aZ[r] + bhz);
      float nn = tanhf(gxn[r] + rr * (aN[r] + bhn));
      float hv = (1.0f - zz) * nn + zz * hprev[r];
      hprev[r] = hv;
      hout[(rloc + r) * 64 + w * 16 + lr] = f2bf(hv);
    }
    __syncthreads();
    // coalesced publish: one 8B agent-atomic store per thread (full lines)
    {
      int row = tid >> 4, c8 = tid & 15;
      unsigned long long val = *(unsigned long long*)&hout[row * 64 + c8 * 4];
      __hip_atomic_store((unsigned long long*)&hnext[(size_t)(rowb + row) * 512 + slc * 64 + c8 * 4],
                         val, __ATOMIC_RELAXED, __HIP_MEMORY_SCOPE_AGENT);
    }
    asm volatile("s_waitcnt vmcnt(0)" ::: "memory");  // h stores at coherence point
    __syncthreads();                 // all threads drained
    if (tid == 0)
      __hip_atomic_store(&gflag[slc], (unsigned)(s + 1), __ATOMIC_RELAXED,
                         __HIP_MEMORY_SCOPE_AGENT);
    // fused deconv for out[:, s-1] — runs in the publish->observe shadow
    if (s >= 1) emit(s - 1);
  }
  // fp32 carry for next chunk
  #pragma unroll
  for (int r = 0; r < 4; r++)
    h_state[(size_t)(rowb + rloc + r) * 512 + j] = hprev[r];
  // final output t=125 from h(126) (only the last chunk)
  if (t0 + Tc == T2){
    if (tid < 8){
      while ((int)__hip_atomic_load(&gflag[tid], __ATOMIC_RELAXED,
                                    __HIP_MEMORY_SCOPE_AGENT) < T2)
        __builtin_amdgcn_s_sleep(1);
    }
    __syncthreads();
    const unsigned short* hbuf = h_glob + (size_t)(T2 & 1) * (512 * 512);
    #pragma unroll
    for (int it = 0; it < 4; it++){
      int cid = tid + 256 * it;
      int row = cid >> 6, ch = cid & 63;
      unsigned long long* src = (unsigned long long*)(hbuf + (size_t)(rowb + row) * 512 + ch * 8);
      unsigned long long lo = __hip_atomic_load(src,     __ATOMIC_RELAXED, __HIP_MEMORY_SCOPE_AGENT);
      unsigned long long hi = __hip_atomic_load(src + 1, __ATOMIC_RELAXED, __HIP_MEMORY_SCOPE_AGENT);
      union { unsigned long long q[2]; us8 v; } u;
      u.q[0] = lo; u.q[1] = hi;
      *(us8*)&hlds[HSWZ(row, ch)] = u.v;
    }
    __syncthreads();
    emit(T2 - 1);
  }
}

extern "C" void kernel_launch(void* const* d_in, const int* in_sizes, int n_in,
                              void* d_out, int out_size, void* d_ws, size_t ws_size,
                              hipStream_t stream) {
  const float* frames   = (const float*)d_in[0];
  const float* conv_w   = (const float*)d_in[1];
  const float* conv_b   = (const float*)d_in[2];
  const float* w_ih     = (const float*)d_in[3];
  const float* w_hh     = (const float*)d_in[4];
  const float* b_ih     = (const float*)d_in[5];
  const float* b_hh     = (const float*)d_in[6];
  const float* deconv_w = (const float*)d_in[7];
  const float* deconv_b = (const float*)d_in[8];
  float* out = (float*)d_out;
  char* ws = (char*)d_ws;

  // fixed region: wih_p 1.5M | whh_p 1.5M | h_state 1M | h_glob 1M | flags 4K
  unsigned short* wih_p   = (unsigned short*)(ws);
  unsigned short* whh_p   = (unsigned short*)(ws + 1572864LL);
  float*          h_state = (float*)         (ws + 3145728LL);
  unsigned short* h_glob  = (unsigned short*)(ws + 4194304LL);
  unsigned int*   flags   = (unsigned int*)  (ws + 5242880LL);
  char*           chunkws = ws + 5246976LL;

  // chunked region: gates 1.5M per timestep (outs eliminated by fusion)
  static const int divs[12] = {126, 63, 42, 21, 18, 14, 9, 7, 6, 3, 2, 1};
  int Tc = 1;
  for (int i = 0; i < 12; i++){
    long long need = 5246976LL + 1572864LL * divs[i];
    if (need <= (long long)ws_size){ Tc = divs[i]; break; }
  }
  int G = T2 / Tc;

  unsigned short* gates_c = (unsigned short*)(chunkws);

  pack_w_kernel<<<384, 256, 0, stream>>>(w_ih, wih_p);
  pack_w_kernel<<<384, 256, 0, stream>>>(w_hh, whh_p);
  scan_init_kernel<<<64, 256, 0, stream>>>(flags, h_glob);

  for (int c = 0; c < G; c++){
    int t0 = c * Tc;
    gates_gemm_kernel<<<8 * Tc, 256, 0, stream>>>(frames, conv_w, conv_b, wih_p,
                                                  b_ih, gates_c, t0, Tc);
    gru_scan_kernel<<<256, 256, 0, stream>>>(gates_c, whh_p, b_hh, h_glob, h_state,
                                             flags, frames, deconv_w, deconv_b, out,
                                             Tc, t0);
  }
}

// Round 7
// 1127.289 us; speedup vs baseline: 1.2193x; 1.1649x over previous
//
#include <hip/hip_runtime.h>
#include <cstdint>

typedef float f32x4 __attribute__((ext_vector_type(4)));
typedef __bf16 bf16x8 __attribute__((ext_vector_type(8)));
typedef unsigned short us8 __attribute__((ext_vector_type(8)));
typedef unsigned long long u64;

#define T2 126

__device__ __forceinline__ unsigned short f2bf(float x){
  union { float f; uint32_t u; } v; v.f = x;
  return (unsigned short)((v.u + 0x7fffu + ((v.u >> 16) & 1u)) >> 16);
}
__device__ __forceinline__ float bf2f(unsigned short h){
  union { uint32_t u; float f; } v; v.u = ((uint32_t)h) << 16; return v.f;
}
__device__ __forceinline__ f32x4 mfma_bf16(us8 a, us8 b, f32x4 c){
  return __builtin_amdgcn_mfma_f32_16x16x32_bf16(
      __builtin_bit_cast(bf16x8, a), __builtin_bit_cast(bf16x8, b), c, 0, 0, 0);
}
__device__ __forceinline__ float sigm(float x){ return 1.0f / (1.0f + __expf(-x)); }

// XOR-swizzled LDS address for a [rows][512] bf16 tile, 8-short chunks.
#define HSWZ(row, chunk) ((row) * 512 + ((((chunk) ^ ((row) & 7))) << 3))

// ---------------------------------------------------------------------------
// Pack (1536,512) fp32 weights -> bf16 MFMA B-fragments.
// Tile (jt,kt): lane l elem e holds W[16jt+(l&15)][32kt+8*(l>>4)+e]
// ---------------------------------------------------------------------------
__global__ void __launch_bounds__(256) pack_w_kernel(const float* __restrict__ w,
                                                     unsigned short* __restrict__ dst){
  int tid = blockIdx.x * 256 + threadIdx.x;     // 0..98303
  int l = tid & 63;
  int tile = tid >> 6;                          // jt*16 + kt
  int kt = tile & 15, jt = tile >> 4;
  int row = jt * 16 + (l & 15);
  int col = kt * 32 + (l >> 4) * 8;
  const float* s = w + (size_t)row * 512 + col;
  unsigned short o[8];
  #pragma unroll
  for (int e = 0; e < 8; e++) o[e] = f2bf(s[e]);
  *(us8*)(dst + (size_t)tid * 8) = *(const us8*)o;
}

// ---------------------------------------------------------------------------
// Fused conv+GELU+GEMM, M-tile 128 (512 thr, 8 waves).
// gates layout (scan-matched): [tl][grp(32)][slc(8)][g(3)][w(4)][lh(4)][r(4)][lr(16)]
// ---------------------------------------------------------------------------
__global__ void __launch_bounds__(512, 1) gates_gemm_kernel(
    const float* __restrict__ frames,
    const float* __restrict__ cw,
    const float* __restrict__ cb,
    const unsigned short* __restrict__ wih_p,
    const float* __restrict__ b_ih,
    unsigned short* __restrict__ gates_c,
    int t0, int Tc){
  __shared__ unsigned short alds[128 * 512];   // 128 KB
  __shared__ float wl[1024];
  __shared__ float cbl[32];
  int tid = threadIdx.x;
  int m0 = blockIdx.x * 128;
  wl[tid] = cw[tid]; wl[tid + 512] = cw[tid + 512];
  if (tid < 32) cbl[tid] = cb[tid];
  __syncthreads();
  // conv+gelu stage into A-tile (2048 tasks = 128 samples x 16 patches)
  #pragma unroll
  for (int tk = 0; tk < 4; tk++){
    int task = tid + 512 * tk;
    int sA = task >> 4, patch = task & 15;
    int n = m0 + sA;
    int b = n / Tc, tl = n - b * Tc;
    int t = t0 + tl;
    const float* fb = frames + ((size_t)b * 128 + t) * 256;
    int ii = patch >> 2, jj = patch & 3;
    float4 pv[4], cv[4];
    #pragma unroll
    for (int p = 0; p < 4; p++){
      int base = (ii * 4 + p) * 16 + jj * 4;
      pv[p] = *(const float4*)(fb + base);          // prev = frame t
      cv[p] = *(const float4*)(fb + 256 + base);    // curr = frame t+1
    }
    #pragma unroll
    for (int o = 0; o < 32; o++){
      const float* wc = &wl[o * 32];
      float acc = cbl[o];
      #pragma unroll
      for (int p = 0; p < 4; p++){
        acc += cv[p].x * wc[p*4+0] + cv[p].y * wc[p*4+1]
             + cv[p].z * wc[p*4+2] + cv[p].w * wc[p*4+3];
        acc += pv[p].x * wc[16+p*4+0] + pv[p].y * wc[16+p*4+1]
             + pv[p].z * wc[16+p*4+2] + pv[p].w * wc[16+p*4+3];
      }
      float g = 0.5f * acc * (1.0f + erff(acc * 0.70710678118654752f));
      int col = o * 16 + patch;
      alds[HSWZ(sA, col >> 3) + (col & 7)] = f2bf(g);
    }
  }
  __syncthreads();
  int l = tid & 63, w = tid >> 6;   // 8 waves
  int lr = l & 15, lh = l >> 4;
  for (int jg = 0; jg < 3; jg++){
    int jt0 = w * 12 + jg * 4;      // wave owns 12 j-tiles
    f32x4 acc[8][4];
    #pragma unroll
    for (int mt = 0; mt < 8; mt++)
      #pragma unroll
      for (int jj = 0; jj < 4; jj++) acc[mt][jj] = (f32x4){0.f,0.f,0.f,0.f};
    #pragma unroll
    for (int kt = 0; kt < 16; kt++){
      us8 a[8], bfr[4];
      #pragma unroll
      for (int mt = 0; mt < 8; mt++)
        a[mt] = *(const us8*)&alds[HSWZ(mt * 16 + lr, kt * 4 + lh)];
      #pragma unroll
      for (int jj = 0; jj < 4; jj++)
        bfr[jj] = *(const us8*)(wih_p + ((size_t)((jt0 + jj) * 16 + kt) * 512 + l * 8));
      #pragma unroll
      for (int mt = 0; mt < 8; mt++)
        #pragma unroll
        for (int jj = 0; jj < 4; jj++)
          acc[mt][jj] = mfma_bf16(a[mt], bfr[jj], acc[mt][jj]);
    }
    #pragma unroll
    for (int jj = 0; jj < 4; jj++){
      int j = (jt0 + jj) * 16 + lr;
      int g = j >> 9, j9 = j & 511;
      int slcT = j9 >> 6, wT = (j9 >> 4) & 3, lrT = j9 & 15;
      int inner = g * 1024 + wT * 256 + lrT;
      float bias = b_ih[j];
      #pragma unroll
      for (int mt = 0; mt < 8; mt++){
        #pragma unroll
        for (int rr = 0; rr < 4; rr++){
          int m = m0 + mt * 16 + lh * 4 + rr;
          int b2 = m / Tc, tl2 = m - b2 * Tc;        // CSE'd across jg/jj
          int grpT = b2 >> 4, lhT = (b2 >> 2) & 3, rT = b2 & 3;
          size_t idx = (((size_t)tl2 * 32 + grpT) * 8 + slcT) * 3072
                     + inner + lhT * 64 + rT * 16;
          gates_c[idx] = f2bf(acc[mt][jj][rr] + bias);
        }
      }
    }
  }
}

// ---------------------------------------------------------------------------
// Per-launch init: parity0 = tag0 (h=0), parity1 = invalid tag 0xFFFF.
// ---------------------------------------------------------------------------
__global__ void __launch_bounds__(256) scan_init_kernel(u64* __restrict__ hpack){
  int tid = blockIdx.x * 256 + threadIdx.x;
  const int total = 512 * 176;
  for (int i = tid; i < total; i += gridDim.x * 256){
    hpack[i] = 0ull;
    hpack[total + i] = 0xFFFFull;
  }
}

// ---------------------------------------------------------------------------
// Weight-stationary persistent GRU scan — tagged-h handoff (no fence, no
// flag, no drain). h words: u64 = [h2|h1|h0|tag16], single-copy atomic.
// Grid = 256 blocks = 32 batch-groups (16 rows) x 8 hidden-slices (64 cols).
// Per step: gx loads || poll 11 tagged words/thread (pipelined) -> unpack
// to swizzled LDS -> 48 MFMA -> gate math -> hout LDS -> pack+publish
// tagged words (fire-and-forget) -> fused deconv emit (in handoff shadow).
// WAR safety: parity double-buffer; observing tag s transitively proves
// consumption of s-1 (same monotone argument as the flag protocol).
// ---------------------------------------------------------------------------
__global__ void __launch_bounds__(256, 1) gru_scan_kernel(
    const unsigned short* __restrict__ gates_c,
    const unsigned short* __restrict__ whh_p,
    const float* __restrict__ b_hh,
    u64* __restrict__ hpack,               // [2][512][176]
    float* __restrict__ h_state,           // [512][512] fp32 chunk carry
    const float* __restrict__ frames,
    const float* __restrict__ dw,
    const float* __restrict__ db,
    float* __restrict__ out,
    int Tc, int t0){
  __shared__ unsigned short hlds[16 * 512];   // h(s) slab, swizzled
  __shared__ unsigned short hout[16 * 64];    // block's h(s+1) tile
  __shared__ float dwl[512];                  // deconv weights
  const int tid = threadIdx.x;
  const int B = blockIdx.x;
  const int grp = B & 31;                     // batch group 0..31
  const int slc = B >> 5;                     // hidden slice 0..7
  const int l = tid & 63;
  const int w = tid >> 6;                     // wave 0..3
  const int lr = l & 15, lh = l >> 4;
  const int j = slc * 64 + w * 16 + lr;       // hidden col
  const int rowb = grp * 16;                  // batch row base
  const int rloc = lh * 4;                    // + r = local row

  dwl[tid] = dw[tid]; dwl[tid + 256] = dw[tid + 256];
  const float dbias = db[0];

  // persistent weight fragments, pinned via volatile loads
  us8 wr[16], wz[16], wn[16];
  {
    const int jt = slc * 4 + w;
    #pragma unroll
    for (int kt = 0; kt < 16; kt++){
      wr[kt] = *(volatile const us8*)(whh_p + ((size_t)((jt      ) * 16 + kt) * 512 + l * 8));
      wz[kt] = *(volatile const us8*)(whh_p + ((size_t)((jt + 32) * 16 + kt) * 512 + l * 8));
      wn[kt] = *(volatile const us8*)(whh_p + ((size_t)((jt + 64) * 16 + kt) * 512 + l * 8));
    }
  }
  const float bhr = b_hh[j], bhz = b_hh[512 + j], bhn = b_hh[1024 + j];
  float hprev[4];
  if (t0 == 0){
    hprev[0] = hprev[1] = hprev[2] = hprev[3] = 0.0f;
  } else {
    #pragma unroll
    for (int r = 0; r < 4; r++) hprev[r] = h_state[(size_t)(rowb + rloc + r) * 512 + j];
  }

  // fused deconv: emit out[:, so] from hlds (= outs[so]); residual frames[b][so+1]
  auto emit = [&](int so){
    int row = tid >> 4;                       // sample row 0..15
    int b = rowb + row;
    const float* fr = frames + ((size_t)b * 128 + so + 1) * 256;
    float* ob = out + ((size_t)b * T2 + so) * 256;
    #pragma unroll
    for (int e = 0; e < 2; e++){
      int pi = (tid & 15) * 2 + e;            // 0..31
      int pr = slc * 2 + (pi >> 4), pc = pi & 15;
      int ii = pr >> 2, pp = pr & 3, jj = pc >> 2, qq = pc & 3;
      float acc = dbias;
      #pragma unroll
      for (int c = 0; c < 32; c++){
        int ch = c * 16 + ii * 4 + jj;
        acc += bf2f(hlds[HSWZ(row, ch >> 3) + (ch & 7)]) * dwl[c * 16 + pp * 4 + qq];
      }
      float dlt = tanhf(acc);
      float rv = fr[pr * 16 + pc] + dlt;
      ob[pr * 16 + pc] = fminf(fmaxf(rv, 0.0f), 1.0f);
    }
  };

  // producer word pack: block region = rows 16 x words [slc*22, slc*22+22)
  auto publish = [&](int wd, unsigned int ptag, u64* wbuf){
    int row = wd / 22, wloc = wd - row * 22;
    int c0 = wloc * 3;
    u64 h0 = hout[row * 64 + c0];
    u64 h1 = 0, h2 = 0;
    if (wloc < 21){ h1 = hout[row * 64 + c0 + 1]; h2 = hout[row * 64 + c0 + 2]; }
    u64 word = (h2 << 48) | (h1 << 32) | (h0 << 16) | (u64)ptag;
    __hip_atomic_store(&wbuf[(size_t)(rowb + row) * 176 + slc * 22 + wloc], word,
                       __ATOMIC_RELAXED, __HIP_MEMORY_SCOPE_AGENT);
  };

  // consumer poll+stage of h(s) into hlds (11 words per thread, exact)
  auto stage = [&](const u64* rbuf, unsigned int want){
    u64 v[11];
    const u64* srcs[11];
    #pragma unroll
    for (int i = 0; i < 11; i++){
      int wd = tid + 256 * i;                 // 0..2815
      int row = wd / 176, widx = wd - row * 176;
      srcs[i] = rbuf + (size_t)(rowb + row) * 176 + widx;
      v[i] = __hip_atomic_load(srcs[i], __ATOMIC_RELAXED, __HIP_MEMORY_SCOPE_AGENT);
    }
    #pragma unroll
    for (int i = 0; i < 11; i++)
      while ((unsigned)(v[i] & 0xFFFFull) != want)
        v[i] = __hip_atomic_load(srcs[i], __ATOMIC_RELAXED, __HIP_MEMORY_SCOPE_AGENT);
    #pragma unroll
    for (int i = 0; i < 11; i++){
      int wd = tid + 256 * i;
      int row = wd / 176, widx = wd - row * 176;
      int sl2 = widx / 22, wl2 = widx - sl2 * 22;
      int c0 = sl2 * 64 + wl2 * 3;
      hlds[HSWZ(row, c0 >> 3) + (c0 & 7)] = (unsigned short)(v[i] >> 16);
      if (wl2 < 21){
        hlds[HSWZ(row, (c0 + 1) >> 3) + ((c0 + 1) & 7)] = (unsigned short)(v[i] >> 32);
        hlds[HSWZ(row, (c0 + 2) >> 3) + ((c0 + 2) & 7)] = (unsigned short)(v[i] >> 48);
      }
    }
  };

  for (int tl = 0; tl < Tc; tl++){
    const int s = t0 + tl;
    const u64* rbuf = hpack + (size_t)(s & 1) * (512 * 176);
    u64* wbuf = hpack + (size_t)((s + 1) & 1) * (512 * 176);
    // gx loads (12 x u16, dense block; complete under the poll)
    const unsigned short* gxp = gates_c
        + ((((size_t)tl * 32 + grp) * 8 + slc) * 3072) + w * 256 + lh * 64 + lr;
    unsigned short gxu[12];
    #pragma unroll
    for (int g = 0; g < 3; g++)
      #pragma unroll
      for (int r = 0; r < 4; r++)
        gxu[g * 4 + r] = gxp[g * 1024 + r * 16];
    __syncthreads();                 // WAR: hlds (prev emit) / hout (prev publish)
    stage(rbuf, (unsigned)s & 0xFFFFu);
    __syncthreads();                 // hlds ready
    f32x4 aR = {0.f,0.f,0.f,0.f}, aZ = {0.f,0.f,0.f,0.f}, aN = {0.f,0.f,0.f,0.f};
    #pragma unroll
    for (int kt = 0; kt < 16; kt++){
      us8 a = *(const us8*)&hlds[HSWZ(lr, kt * 4 + lh)];
      aR = mfma_bf16(a, wr[kt], aR);
      aZ = mfma_bf16(a, wz[kt], aZ);
      aN = mfma_bf16(a, wn[kt], aN);
    }
    #pragma unroll
    for (int r = 0; r < 4; r++){
      float rr = sigm(bf2f(gxu[r]) + aR[r] + bhr);
      float zz = sigm(bf2f(gxu[4 + r]) + aZ[r] + bhz);
      float nn = tanhf(bf2f(gxu[8 + r]) + rr * (aN[r] + bhn));
      float hv = (1.0f - zz) * nn + zz * hprev[r];
      hprev[r] = hv;
      hout[(rloc + r) * 64 + w * 16 + lr] = f2bf(hv);
    }
    __syncthreads();                 // hout ready
    unsigned int ptag = (unsigned)(s + 1) & 0xFFFFu;
    publish(tid, ptag, wbuf);
    if (tid < 96) publish(256 + tid, ptag, wbuf);
    // fused deconv for out[:, s-1] — runs in the handoff shadow
    if (s >= 1) emit(s - 1);
  }
  // fp32 carry for next chunk
  #pragma unroll
  for (int r = 0; r < 4; r++)
    h_state[(size_t)(rowb + rloc + r) * 512 + j] = hprev[r];
  // final output t=125 from h(126) (only the last chunk)
  if (t0 + Tc == T2){
    __syncthreads();                 // WAR: hlds vs last emit
    stage(hpack + (size_t)(T2 & 1) * (512 * 176), (unsigned)T2 & 0xFFFFu);
    __syncthreads();
    emit(T2 - 1);
  }
}

extern "C" void kernel_launch(void* const* d_in, const int* in_sizes, int n_in,
                              void* d_out, int out_size, void* d_ws, size_t ws_size,
                              hipStream_t stream) {
  const float* frames   = (const float*)d_in[0];
  const float* conv_w   = (const float*)d_in[1];
  const float* conv_b   = (const float*)d_in[2];
  const float* w_ih     = (const float*)d_in[3];
  const float* w_hh     = (const float*)d_in[4];
  const float* b_ih     = (const float*)d_in[5];
  const float* b_hh     = (const float*)d_in[6];
  const float* deconv_w = (const float*)d_in[7];
  const float* deconv_b = (const float*)d_in[8];
  float* out = (float*)d_out;
  char* ws = (char*)d_ws;

  // fixed: wih_p 1.5M | whh_p 1.5M | h_state 1M | hpack 1.44M
  unsigned short* wih_p   = (unsigned short*)(ws);
  unsigned short* whh_p   = (unsigned short*)(ws + 1572864LL);
  float*          h_state = (float*)         (ws + 3145728LL);
  u64*            hpack   = (u64*)           (ws + 4194304LL);   // 1,441,792 B
  char*           chunkws = ws + 5636096LL;

  // chunked region: gates 1,572,864 B per timestep
  static const int divs[12] = {126, 63, 42, 21, 18, 14, 9, 7, 6, 3, 2, 1};
  int Tc = 1;
  for (int i = 0; i < 12; i++){
    long long need = 5636096LL + 1572864LL * divs[i];
    if (need <= (long long)ws_size){ Tc = divs[i]; break; }
  }
  int G = T2 / Tc;

  unsigned short* gates_c = (unsigned short*)(chunkws);

  pack_w_kernel<<<384, 256, 0, stream>>>(w_ih, wih_p);
  pack_w_kernel<<<384, 256, 0, stream>>>(w_hh, whh_p);
  scan_init_kernel<<<64, 256, 0, stream>>>(hpack);

  for (int c = 0; c < G; c++){
    int t0 = c * Tc;
    gates_gemm_kernel<<<4 * Tc, 512, 0, stream>>>(frames, conv_w, conv_b, wih_p,
                                                  b_ih, gates_c, t0, Tc);
    gru_scan_kernel<<<256, 256, 0, stream>>>(gates_c, whh_p, b_hh, hpack, h_state,
                                             frames, deconv_w, deconv_b, out,
                                             Tc, t0);
  }
}

// Round 9
// 855.512 us; speedup vs baseline: 1.6067x; 1.3177x over previous
//
#include <hip/hip_runtime.h>
#include <cstdint>

typedef float f32x4 __attribute__((ext_vector_type(4)));
typedef __bf16 bf16x8 __attribute__((ext_vector_type(8)));
typedef unsigned short us8 __attribute__((ext_vector_type(8)));
typedef unsigned int u32x4 __attribute__((ext_vector_type(4)));
typedef unsigned long long u64;

#define T2 126

__device__ __forceinline__ unsigned short f2bf(float x){
  union { float f; uint32_t u; } v; v.f = x;
  return (unsigned short)((v.u + 0x7fffu + ((v.u >> 16) & 1u)) >> 16);
}
__device__ __forceinline__ float bf2f(unsigned short h){
  union { uint32_t u; float f; } v; v.u = ((uint32_t)h) << 16; return v.f;
}
__device__ __forceinline__ f32x4 mfma_bf16(us8 a, us8 b, f32x4 c){
  return __builtin_amdgcn_mfma_f32_16x16x32_bf16(
      __builtin_bit_cast(bf16x8, a), __builtin_bit_cast(bf16x8, b), c, 0, 0, 0);
}
__device__ __forceinline__ float sigm(float x){ return 1.0f / (1.0f + __expf(-x)); }

// XOR-swizzled LDS address for a [rows][512] bf16 tile, 8-short (16B) chunks.
#define HSWZ(row, chunk) ((row) * 512 + ((((chunk) ^ ((row) & 7))) << 3))

// ---------------------------------------------------------------------------
// Pack (1536,512) fp32 weights -> bf16 MFMA B-fragments.
// ---------------------------------------------------------------------------
__global__ void __launch_bounds__(256) pack_w_kernel(const float* __restrict__ w,
                                                     unsigned short* __restrict__ dst){
  int tid = blockIdx.x * 256 + threadIdx.x;     // 0..98303
  int l = tid & 63;
  int tile = tid >> 6;                          // jt*16 + kt
  int kt = tile & 15, jt = tile >> 4;
  int row = jt * 16 + (l & 15);
  int col = kt * 32 + (l >> 4) * 8;
  const float* s = w + (size_t)row * 512 + col;
  unsigned short o[8];
  #pragma unroll
  for (int e = 0; e < 8; e++) o[e] = f2bf(s[e]);
  *(us8*)(dst + (size_t)tid * 8) = *(const us8*)o;
}

// ---------------------------------------------------------------------------
// Fused conv+GELU+GEMM, M-tile = 16 batch rows x 7 timesteps (112 samples).
// mt <-> t, lane row (lh*4+r) <-> batch-in-group: C-stores land as wave-
// coalesced 32B segments in the scan-matched gates layout
// [tl][grp(32)][slc(8)][g(3)][wT(4)][i(16)][lr(16)]  (3072 u16 per (tl,grp,slc))
// ---------------------------------------------------------------------------
__global__ void __launch_bounds__(512, 1) gates_gemm_kernel(
    const float* __restrict__ frames,
    const float* __restrict__ cw,
    const float* __restrict__ cb,
    const unsigned short* __restrict__ wih_p,
    const float* __restrict__ b_ih,
    unsigned short* __restrict__ gates_c,
    int t0, int Tc){
  __shared__ unsigned short alds[112 * 512];   // 114,688 B
  __shared__ float wl[1024];
  __shared__ float cbl[32];
  int tid = threadIdx.x;
  int grp = blockIdx.x & 31;
  int tlc = blockIdx.x >> 5;
  wl[tid] = cw[tid]; wl[tid + 512] = cw[tid + 512];
  if (tid < 32) cbl[tid] = cb[tid];
  __syncthreads();
  // conv+gelu stage: 1792 tasks = 112 samples x 16 patches
  #pragma unroll
  for (int tk = 0; tk < 4; tk++){
    int task = tid + 512 * tk;
    if (task < 1792){
      int sA = task >> 4, patch = task & 15;
      int t7 = sA >> 4, i = sA & 15;            // sA = t7*16 + i
      int tl = tlc * 7 + t7;
      int b = grp * 16 + i;
      int t = t0 + tl;
      const float* fb = frames + ((size_t)b * 128 + t) * 256;
      int ii = patch >> 2, jj = patch & 3;
      float4 pv[4], cv[4];
      #pragma unroll
      for (int p = 0; p < 4; p++){
        int base = (ii * 4 + p) * 16 + jj * 4;
        pv[p] = *(const float4*)(fb + base);          // prev = frame t
        cv[p] = *(const float4*)(fb + 256 + base);    // curr = frame t+1
      }
      #pragma unroll
      for (int o = 0; o < 32; o++){
        const float* wc = &wl[o * 32];
        float acc = cbl[o];
        #pragma unroll
        for (int p = 0; p < 4; p++){
          acc += cv[p].x * wc[p*4+0] + cv[p].y * wc[p*4+1]
               + cv[p].z * wc[p*4+2] + cv[p].w * wc[p*4+3];
          acc += pv[p].x * wc[16+p*4+0] + pv[p].y * wc[16+p*4+1]
               + pv[p].z * wc[16+p*4+2] + pv[p].w * wc[16+p*4+3];
        }
        float g = 0.5f * acc * (1.0f + erff(acc * 0.70710678118654752f));
        int col = o * 16 + patch;
        alds[HSWZ(sA, col >> 3) + (col & 7)] = f2bf(g);
      }
    }
  }
  __syncthreads();
  int l = tid & 63, w = tid >> 6;   // 8 waves
  int lr = l & 15, lh = l >> 4;
  for (int jg = 0; jg < 3; jg++){
    int jt0 = w * 12 + jg * 4;
    int q4 = w * 3 + jg;            // jt0/4: 0..23
    int g = q4 >> 3, slcT = q4 & 7;
    f32x4 acc[7][4];
    #pragma unroll
    for (int mt = 0; mt < 7; mt++)
      #pragma unroll
      for (int jj = 0; jj < 4; jj++) acc[mt][jj] = (f32x4){0.f,0.f,0.f,0.f};
    #pragma unroll
    for (int kt = 0; kt < 16; kt++){
      us8 a[7], bfr[4];
      #pragma unroll
      for (int mt = 0; mt < 7; mt++)
        a[mt] = *(const us8*)&alds[HSWZ(mt * 16 + lr, kt * 4 + lh)];
      #pragma unroll
      for (int jj = 0; jj < 4; jj++)
        bfr[jj] = *(const us8*)(wih_p + ((size_t)((jt0 + jj) * 16 + kt) * 512 + l * 8));
      #pragma unroll
      for (int mt = 0; mt < 7; mt++)
        #pragma unroll
        for (int jj = 0; jj < 4; jj++)
          acc[mt][jj] = mfma_bf16(a[mt], bfr[jj], acc[mt][jj]);
    }
    #pragma unroll
    for (int jj = 0; jj < 4; jj++){
      float bias = b_ih[(jt0 + jj) * 16 + lr];
      #pragma unroll
      for (int mt = 0; mt < 7; mt++){
        size_t base2 = (((size_t)(tlc * 7 + mt) * 32 + grp) * 8 + slcT) * 3072
                     + g * 1024 + jj * 256 + lr;
        #pragma unroll
        for (int rr = 0; rr < 4; rr++)
          gates_c[base2 + (lh * 4 + rr) * 16] = f2bf(acc[mt][jj][rr] + bias);
      }
    }
  }
}

// ---------------------------------------------------------------------------
// Per-launch init: hq parity0 = h(0) = 0; tags parity0 = 0, parity1 = invalid.
// ---------------------------------------------------------------------------
__global__ void __launch_bounds__(256) scan_init_kernel(u32x4* __restrict__ hq,
                                                        unsigned short* __restrict__ htag){
  int tid = blockIdx.x * 256 + threadIdx.x;
  int stride = gridDim.x * 256;
  for (int i = tid; i < 32768; i += stride)
    hq[i] = (u32x4){0u, 0u, 0u, 0u};
  for (int i = tid; i < 4096; i += stride){
    htag[i] = 0;
    htag[4096 + i] = 0xFFFFu;
  }
}

// ---------------------------------------------------------------------------
// Weight-stationary persistent GRU scan — quad-granular coherent exchange.
// Grid = 256 blocks = 32 batch-groups (16 rows) x 8 hidden-slices (64 cols).
// h exchange: hq[2][512 rows][64 quads] (16B quads, sc0+sc1 bypass loads/
// stores) + htag[2][512][8] u16 row tags. Producer: 8 quad-stores per row
// (same wave), vmcnt(0), then row tag store => tag observed implies data
// visible. Consumer: poll 16 row-tag quads (8 tags each), barrier, then
// 16B loads straight into ds_write_b128 (no unpack, conflict-clean).
// Monotone tags + parity double-buffer => no WAR hazard (same argument as
// the flag protocol). Fused deconv emit in the handoff shadow.
// ---------------------------------------------------------------------------
__global__ void __launch_bounds__(256, 1) gru_scan_kernel(
    const unsigned short* __restrict__ gates_c,
    const unsigned short* __restrict__ whh_p,
    const float* __restrict__ b_hh,
    u32x4* __restrict__ hq,                // [2][512][64] quads
    unsigned short* __restrict__ htag,     // [2][512][8]
    float* __restrict__ h_state,           // [512][512] fp32 chunk carry
    const float* __restrict__ frames,
    const float* __restrict__ dw,
    const float* __restrict__ db,
    float* __restrict__ out,
    int Tc, int t0){
  __shared__ unsigned short hlds[16 * 512];   // h(s) slab, swizzled
  __shared__ unsigned short hout[16 * 64];    // block's h(s+1) tile
  __shared__ float dwl[512];                  // deconv weights
  const int tid = threadIdx.x;
  const int B = blockIdx.x;
  const int grp = B & 31;                     // batch group 0..31
  const int slc = B >> 5;                     // hidden slice 0..7
  const int l = tid & 63;
  const int w = tid >> 6;                     // wave 0..3
  const int lr = l & 15, lh = l >> 4;
  const int j = slc * 64 + w * 16 + lr;       // hidden col
  const int rowb = grp * 16;                  // batch row base
  const int rloc = lh * 4;                    // + r = local row

  dwl[tid] = dw[tid]; dwl[tid + 256] = dw[tid + 256];
  const float dbias = db[0];

  // persistent weight fragments, pinned via volatile loads
  us8 wr[16], wz[16], wn[16];
  {
    const int jt = slc * 4 + w;
    #pragma unroll
    for (int kt = 0; kt < 16; kt++){
      wr[kt] = *(volatile const us8*)(whh_p + ((size_t)((jt      ) * 16 + kt) * 512 + l * 8));
      wz[kt] = *(volatile const us8*)(whh_p + ((size_t)((jt + 32) * 16 + kt) * 512 + l * 8));
      wn[kt] = *(volatile const us8*)(whh_p + ((size_t)((jt + 64) * 16 + kt) * 512 + l * 8));
    }
  }
  const float bhr = b_hh[j], bhz = b_hh[512 + j], bhn = b_hh[1024 + j];
  float hprev[4];
  if (t0 == 0){
    hprev[0] = hprev[1] = hprev[2] = hprev[3] = 0.0f;
  } else {
    #pragma unroll
    for (int r = 0; r < 4; r++) hprev[r] = h_state[(size_t)(rowb + rloc + r) * 512 + j];
  }

  // fused deconv: emit out[:, so] from hlds (= h(so+1)); residual frames[b][so+1]
  auto emit = [&](int so){
    int row = tid >> 4;                       // sample row 0..15
    int b = rowb + row;
    const float* fr = frames + ((size_t)b * 128 + so + 1) * 256;
    float* ob = out + ((size_t)b * T2 + so) * 256;
    #pragma unroll
    for (int e = 0; e < 2; e++){
      int pi = (tid & 15) * 2 + e;            // 0..31
      int pr = slc * 2 + (pi >> 4), pc = pi & 15;
      int ii = pr >> 2, pp = pr & 3, jj2 = pc >> 2, qq = pc & 3;
      float acc = dbias;
      #pragma unroll
      for (int c = 0; c < 32; c++){
        int ch = c * 16 + ii * 4 + jj2;
        acc += bf2f(hlds[HSWZ(row, ch >> 3) + (ch & 7)]) * dwl[c * 16 + pp * 4 + qq];
      }
      float dlt = tanhf(acc);
      float rv = fr[pr * 16 + pc] + dlt;
      ob[pr * 16 + pc] = fminf(fmaxf(rv, 0.0f), 1.0f);
    }
  };

  // poll row tags for step s (parity s&1), then barrier
  auto poll = [&](int s){
    if (tid < 16){
      const u32x4* tp = (const u32x4*)(htag + ((size_t)(s & 1) * 512 + rowb + tid) * 8);
      unsigned int want = (unsigned)s * 0x00010001u;
      for (;;){
        u32x4 tv;
        asm volatile("global_load_dwordx4 %0, %1, off sc0 sc1\n\ts_waitcnt vmcnt(0)"
                     : "=&v"(tv) : "v"(tp) : "memory");
        if (tv[0] == want && tv[1] == want && tv[2] == want && tv[3] == want) break;
        __builtin_amdgcn_s_sleep(1);
      }
    }
    __syncthreads();
  };

  // stage h(s) slab (16 rows x 64 quads) -> hlds, 4 quads/thread
  auto stage = [&](int s){
    const u32x4* rb = hq + (size_t)(s & 1) * 32768;
    int quad = tid & 63, r0 = tid >> 6;       // r0 0..3
    const u32x4* p0 = rb + ((size_t)(rowb + r0) * 64 + quad);
    const u32x4* p1 = p0 + 4 * 64;
    const u32x4* p2 = p0 + 8 * 64;
    const u32x4* p3 = p0 + 12 * 64;
    u32x4 q0, q1, q2, q3;
    asm volatile(
      "global_load_dwordx4 %0, %4, off sc0 sc1\n\t"
      "global_load_dwordx4 %1, %5, off sc0 sc1\n\t"
      "global_load_dwordx4 %2, %6, off sc0 sc1\n\t"
      "global_load_dwordx4 %3, %7, off sc0 sc1\n\t"
      "s_waitcnt vmcnt(0)"
      : "=&v"(q0), "=&v"(q1), "=&v"(q2), "=&v"(q3)
      : "v"(p0), "v"(p1), "v"(p2), "v"(p3)
      : "memory");
    *(u32x4*)&hlds[HSWZ(r0,      quad)] = q0;
    *(u32x4*)&hlds[HSWZ(r0 + 4,  quad)] = q1;
    *(u32x4*)&hlds[HSWZ(r0 + 8,  quad)] = q2;
    *(u32x4*)&hlds[HSWZ(r0 + 12, quad)] = q3;
    __syncthreads();
  };

  for (int tl = 0; tl < Tc; tl++){
    const int s = t0 + tl;
    // gx loads (12 x u16, dense block; complete under the poll)
    const unsigned short* gxp = gates_c
        + ((((size_t)tl * 32 + grp) * 8 + slc) * 3072) + w * 256 + lh * 64 + lr;
    unsigned short gxu[12];
    #pragma unroll
    for (int g = 0; g < 3; g++)
      #pragma unroll
      for (int r = 0; r < 4; r++)
        gxu[g * 4 + r] = gxp[g * 1024 + r * 16];
    poll(s);                         // also WAR barrier: hlds/hout reuse
    stage(s);
    f32x4 aR = {0.f,0.f,0.f,0.f}, aZ = {0.f,0.f,0.f,0.f}, aN = {0.f,0.f,0.f,0.f};
    #pragma unroll
    for (int kt = 0; kt < 16; kt++){
      us8 a = *(const us8*)&hlds[HSWZ(lr, kt * 4 + lh)];
      aR = mfma_bf16(a, wr[kt], aR);
      aZ = mfma_bf16(a, wz[kt], aZ);
      aN = mfma_bf16(a, wn[kt], aN);
    }
    #pragma unroll
    for (int r = 0; r < 4; r++){
      float rr = sigm(bf2f(gxu[r]) + aR[r] + bhr);
      float zz = sigm(bf2f(gxu[4 + r]) + aZ[r] + bhz);
      float nn = tanhf(bf2f(gxu[8 + r]) + rr * (aN[r] + bhn));
      float hv = (1.0f - zz) * nn + zz * hprev[r];
      hprev[r] = hv;
      hout[(rloc + r) * 64 + w * 16 + lr] = f2bf(hv);
    }
    __syncthreads();                 // hout ready
    // publish: 8 quad stores per row (one wave owns a row) -> drain -> tag
    if (tid < 128){
      int row = tid >> 3, q = tid & 7;
      u32x4 hv = *(const u32x4*)&hout[row * 64 + q * 8];
      u32x4* dst = hq + ((size_t)(((s + 1) & 1) * 512 + rowb + row) * 64 + slc * 8 + q);
      asm volatile("global_store_dwordx4 %0, %1, off sc0 sc1" :: "v"(dst), "v"(hv) : "memory");
      asm volatile("s_waitcnt vmcnt(0)" ::: "memory");
      if (q == 0){
        unsigned int tg = (unsigned)(s + 1);
        unsigned short* tp = htag + ((size_t)((s + 1) & 1) * 512 + rowb + row) * 8 + slc;
        asm volatile("global_store_short %0, %1, off sc0 sc1" :: "v"(tp), "v"(tg) : "memory");
      }
    }
    // fused deconv for out[:, s-1] — runs in the handoff shadow
    if (s >= 1) emit(s - 1);
  }
  // fp32 carry for next chunk
  #pragma unroll
  for (int r = 0; r < 4; r++)
    h_state[(size_t)(rowb + rloc + r) * 512 + j] = hprev[r];
  // final output t=125 from h(126) (only the last chunk)
  if (t0 + Tc == T2){
    poll(T2);                        // barrier also WAR-protects hlds vs last emit
    stage(T2);
    emit(T2 - 1);
  }
}

extern "C" void kernel_launch(void* const* d_in, const int* in_sizes, int n_in,
                              void* d_out, int out_size, void* d_ws, size_t ws_size,
                              hipStream_t stream) {
  const float* frames   = (const float*)d_in[0];
  const float* conv_w   = (const float*)d_in[1];
  const float* conv_b   = (const float*)d_in[2];
  const float* w_ih     = (const float*)d_in[3];
  const float* w_hh     = (const float*)d_in[4];
  const float* b_ih     = (const float*)d_in[5];
  const float* b_hh     = (const float*)d_in[6];
  const float* deconv_w = (const float*)d_in[7];
  const float* deconv_b = (const float*)d_in[8];
  float* out = (float*)d_out;
  char* ws = (char*)d_ws;

  // fixed: wih_p 1.5M | whh_p 1.5M | h_state 1M | hq 1M | htag 16K
  unsigned short* wih_p   = (unsigned short*)(ws);
  unsigned short* whh_p   = (unsigned short*)(ws + 1572864LL);
  float*          h_state = (float*)         (ws + 3145728LL);
  u32x4*          hq      = (u32x4*)         (ws + 4194304LL);
  unsigned short* htag    = (unsigned short*)(ws + 5242880LL);
  char*           chunkws = ws + 5259264LL;

  // chunked region: gates 1,572,864 B per timestep; Tc must be a multiple
  // of 7 (gemm M-tile = 16 batch x 7 timesteps)
  static const int divs[6] = {126, 63, 42, 21, 14, 7};
  int Tc = 7;
  for (int i = 0; i < 6; i++){
    long long need = 5259264LL + 1572864LL * divs[i];
    if (need <= (long long)ws_size){ Tc = divs[i]; break; }
  }
  int G = T2 / Tc;

  unsigned short* gates_c = (unsigned short*)(chunkws);

  pack_w_kernel<<<384, 256, 0, stream>>>(w_ih, wih_p);
  pack_w_kernel<<<384, 256, 0, stream>>>(w_hh, whh_p);
  scan_init_kernel<<<64, 256, 0, stream>>>(hq, htag);

  for (int c = 0; c < G; c++){
    int t0 = c * Tc;
    gates_gemm_kernel<<<32 * (Tc / 7), 512, 0, stream>>>(frames, conv_w, conv_b, wih_p,
                                                         b_ih, gates_c, t0, Tc);
    gru_scan_kernel<<<256, 256, 0, stream>>>(gates_c, whh_p, b_hh, hq, htag, h_state,
                                             frames, deconv_w, deconv_b, out,
                                             Tc, t0);
  }
}